// Round 10
// baseline (1092.541 us; speedup 1.0000x reference)
//
#include <hip/hip_runtime.h>
#include <hip/hip_bf16.h>
#include <stdint.h>

typedef __attribute__((ext_vector_type(8))) short short8;
typedef __attribute__((ext_vector_type(4))) float f32x4;

__device__ __forceinline__ float b2f(short s) {
    union { unsigned u; float f; } v; v.u = ((unsigned)(unsigned short)s) << 16; return v.f;
}
__device__ __forceinline__ short f2b(float f) {
    union { float f; unsigned u; } v; v.f = f;
    unsigned r = (v.u + 0x7FFF + ((v.u >> 16) & 1)) >> 16;
    return (short)r;
}

// async global->LDS, 16B per lane. LDS dest is wave-uniform base + lane*16.
__device__ __forceinline__ void gload16(const void* g, void* l) {
    __builtin_amdgcn_global_load_lds(
        (const __attribute__((address_space(1))) void*)(uintptr_t)g,
        (__attribute__((address_space(3))) void*)(uintptr_t)l,
        16, 0, 0);
}

#define BAR()     asm volatile("s_barrier" ::: "memory")
#define WAITV0()  asm volatile("s_waitcnt vmcnt(0)" ::: "memory")

// ---------------- cast fp32 -> bf16 (8 elems/thread) ----------------
__global__ __launch_bounds__(256) void cast_bf16_kernel(
    const float* __restrict__ src, short* __restrict__ dst, int n8) {
    int i = blockIdx.x * 256 + threadIdx.x;
    if (i >= n8) return;
    const float4* s = (const float4*)src + (size_t)i * 2;
    float4 x0 = s[0], x1 = s[1];
    short8 o;
    o[0] = f2b(x0.x); o[1] = f2b(x0.y); o[2] = f2b(x0.z); o[3] = f2b(x0.w);
    o[4] = f2b(x1.x); o[5] = f2b(x1.y); o[6] = f2b(x1.z); o[7] = f2b(x1.w);
    *((short8*)dst + i) = o;
}

// ---------- transpose-cast W[K,N] f32 -> Wt[N,K] bf16 (8 k per thread) ----------
__global__ __launch_bounds__(256) void transpose_cast_kernel(
    const float* __restrict__ W, short* __restrict__ Wt, int K, int N, int total) {
    int t = blockIdx.x * 256 + threadIdx.x;
    if (t >= total) return;
    const float* src = W + (size_t)blockIdx.y * K * N;
    short* dst = Wt + (size_t)blockIdx.y * K * N;
    int n = t % N;
    int k0 = (t / N) * 8;
    short8 o;
#pragma unroll
    for (int i = 0; i < 8; i++) o[i] = f2b(src[(size_t)(k0 + i) * N + n]);
    *(short8*)(dst + (size_t)n * K + k0) = o;
}

// ============ m97-structure 128x128 GEMM: C = relu(A @ Bt^T + bias), bf16 out ============
// 4 waves, BK=32, 16KB LDS, 3 blocks/CU (TLP covers barrier drains — m114/m97).
// N is the C ROW-STRIDE only (grid covers the full panel width).
// DUAL=1: cols >= 1024 go to C2 (bias2, row stride 256).
// NOTE R9 bug: passed N=1280 for the dual launch — C stride must be 1024.
template<int DUAL>
__global__ __launch_bounds__(256, 3)
void gemm_bt_bias_relu(const short* __restrict__ A, const short* __restrict__ Bt,
                       const float* __restrict__ bias, short* __restrict__ C,
                       const float* __restrict__ bias2, short* __restrict__ C2,
                       int M, int N, int K) {
    __shared__ __align__(16) short As[128 * 32];
    __shared__ __align__(16) short Bs[128 * 32];
    const int tid = threadIdx.x;
    const int w = tid >> 6, lane = tid & 63;
    const int tm = blockIdx.y * 128, tn = blockIdx.x * 128;
    const int wm = (w & 1) * 64, wn = (w >> 1) * 64;
    const int r = lane & 15, q = lane >> 4, qk = q * 8;

    const int c0 = w * 2, c1 = w * 2 + 1;
    const int srow0 = c0 * 16 + (lane >> 2);
    const int srow1 = c1 * 16 + (lane >> 2);
    const int skk = (lane & 3) * 8;
    const short* gA0 = A + (size_t)(tm + srow0) * K + skk;
    const short* gA1 = A + (size_t)(tm + srow1) * K + skk;
    const short* gB0 = Bt + (size_t)(tn + srow0) * K + skk;
    const short* gB1 = Bt + (size_t)(tn + srow1) * K + skk;
    short* lA0 = &As[c0 * 512]; short* lA1 = &As[c1 * 512];
    short* lB0 = &Bs[c0 * 512]; short* lB1 = &Bs[c1 * 512];

    f32x4 acc[4][4] = {};
    for (int k0 = 0; k0 < K; k0 += 32) {
        gload16(gA0 + k0, lA0);
        gload16(gA1 + k0, lA1);
        gload16(gB0 + k0, lB0);
        gload16(gB1 + k0, lB1);
        __syncthreads();
        short8 a[4], b[4];
#pragma unroll
        for (int i = 0; i < 4; i++) a[i] = *(const short8*)&As[(wm + i * 16 + r) * 32 + qk];
#pragma unroll
        for (int j = 0; j < 4; j++) b[j] = *(const short8*)&Bs[(wn + j * 16 + r) * 32 + qk];
#pragma unroll
        for (int i = 0; i < 4; i++)
#pragma unroll
            for (int j = 0; j < 4; j++)
                acc[i][j] = __builtin_amdgcn_mfma_f32_16x16x32_bf16(a[i], b[j], acc[i][j], 0, 0, 0);
        __syncthreads();
    }
#pragma unroll
    for (int j = 0; j < 4; j++) {
        int col = tn + wn + j * 16 + r;
        float bj = (DUAL && col >= 1024) ? bias2[col - 1024] : bias[col];
#pragma unroll
        for (int i = 0; i < 4; i++)
#pragma unroll
            for (int rr = 0; rr < 4; rr++) {
                int row = tm + wm + i * 16 + q * 4 + rr;
                float v = fmaxf(acc[i][j][rr] + bj, 0.f);
                if (DUAL && col >= 1024)
                    C2[(size_t)row * 256 + (col - 1024)] = f2b(v);
                else
                    C[(size_t)row * N + col] = f2b(v);
            }
    }
}

// ---------------- fused selector: s0 -> s1 -> logits -> softmax -> wsel ----------------
__global__ __launch_bounds__(256, 3)
void sel_fused(const short* __restrict__ s0, const short* __restrict__ Ws1t,
               const float* __restrict__ bs1, const short* __restrict__ Ws2t,
               const float* __restrict__ bs2, float* __restrict__ wsel) {
    __shared__ __align__(16) short As[128 * 32];
    __shared__ __align__(16) short Bs[128 * 32];
    __shared__ __align__(16) short s1l[128 * 136];
    const int tid = threadIdx.x;
    const int w = tid >> 6, lane = tid & 63;
    const int tm = blockIdx.x * 128;
    const int wm = (w & 1) * 64, wn = (w >> 1) * 64;
    const int r = lane & 15, q = lane >> 4, qk = q * 8;

    const int c0 = w * 2, c1 = w * 2 + 1;
    const int srow0 = c0 * 16 + (lane >> 2);
    const int srow1 = c1 * 16 + (lane >> 2);
    const int skk = (lane & 3) * 8;
    const short* gA0 = s0 + (size_t)(tm + srow0) * 256 + skk;
    const short* gA1 = s0 + (size_t)(tm + srow1) * 256 + skk;
    const short* gB0 = Ws1t + (size_t)srow0 * 256 + skk;
    const short* gB1 = Ws1t + (size_t)srow1 * 256 + skk;
    short* lA0 = &As[c0 * 512]; short* lA1 = &As[c1 * 512];
    short* lB0 = &Bs[c0 * 512]; short* lB1 = &Bs[c1 * 512];

    f32x4 acc[4][4] = {};
    for (int k0 = 0; k0 < 256; k0 += 32) {
        gload16(gA0 + k0, lA0);
        gload16(gA1 + k0, lA1);
        gload16(gB0 + k0, lB0);
        gload16(gB1 + k0, lB1);
        __syncthreads();
        short8 a[4], b[4];
#pragma unroll
        for (int i = 0; i < 4; i++) a[i] = *(const short8*)&As[(wm + i * 16 + r) * 32 + qk];
#pragma unroll
        for (int j = 0; j < 4; j++) b[j] = *(const short8*)&Bs[(wn + j * 16 + r) * 32 + qk];
#pragma unroll
        for (int i = 0; i < 4; i++)
#pragma unroll
            for (int j = 0; j < 4; j++)
                acc[i][j] = __builtin_amdgcn_mfma_f32_16x16x32_bf16(a[i], b[j], acc[i][j], 0, 0, 0);
        __syncthreads();
    }
#pragma unroll
    for (int j = 0; j < 4; j++) {
        int col = wn + j * 16 + r;
        float bj = bs1[col];
#pragma unroll
        for (int i = 0; i < 4; i++)
#pragma unroll
            for (int rr = 0; rr < 4; rr++) {
                int row = wm + i * 16 + q * 4 + rr;
                s1l[row * 136 + col] = f2b(fmaxf(acc[i][j][rr] + bj, 0.f));
            }
    }
    __syncthreads();
    f32x4 acc3[2] = {};
#pragma unroll
    for (int k3 = 0; k3 < 4; ++k3) {
        short8 b3 = *(const short8*)(Ws2t + (size_t)r * 128 + k3 * 32 + qk);
#pragma unroll
        for (int m2 = 0; m2 < 2; m2++) {
            short8 a3 = *(const short8*)&s1l[(w * 32 + m2 * 16 + r) * 136 + k3 * 32 + qk];
            acc3[m2] = __builtin_amdgcn_mfma_f32_16x16x32_bf16(a3, b3, acc3[m2], 0, 0, 0);
        }
    }
    float bse = bs2[r];
#pragma unroll
    for (int m2 = 0; m2 < 2; m2++)
#pragma unroll
        for (int rr = 0; rr < 4; rr++) {
            int row = tm + w * 32 + m2 * 16 + q * 4 + rr;
            float v = acc3[m2][rr] + bse;
            float m = v;
#pragma unroll
            for (int off = 8; off >= 1; off >>= 1) m = fmaxf(m, __shfl_xor(m, off, 16));
            float ex = __expf(v - m);
            float s = ex;
#pragma unroll
            for (int off = 8; off >= 1; off >>= 1) s += __shfl_xor(s, off, 16);
            wsel[(size_t)row * 16 + r] = ex / s;
        }
}

// ------- reduce: out[i][a] = sum_e wsel[i,e]*be2[e,a] + sum_bx partial[by][bx][r][a] -------
__global__ __launch_bounds__(256)
void reduce_kernel(const float* __restrict__ partial, const float* __restrict__ wsel,
                   const float* __restrict__ be2, float* __restrict__ out) {
    int t = blockIdx.x * 256 + threadIdx.x;      // B * 8 threads
    int a4 = t & 7, i = t >> 3;
    int by = i >> 8, r = i & 255;
    const float* p = partial + (size_t)by * 16 * 8192 + r * 32 + a4 * 4;
    const float* wr = wsel + (size_t)i * 16;
    f32x4 s = {};
#pragma unroll
    for (int e = 0; e < 16; e++) {
        float wv = wr[e];
        const float* b2 = be2 + e * 32 + a4 * 4;
#pragma unroll
        for (int j = 0; j < 4; j++) s[j] = fmaf(wv, b2[j], s[j]);
    }
#pragma unroll
    for (int bx = 0; bx < 16; bx++) s += *(const f32x4*)(p + (size_t)bx * 8192);
    *(f32x4*)(out + (size_t)i * 32 + a4 * 4) = s;
}

// ================= 256x256 GEMM (MODE 2 expert only) — reg-pipelined, 1 barrier/tile ========
// 8 waves (2Mx4N), BK=64, LDS 128KiB double-buffered, swizzle byte ^= (row&7)<<4.
// Boundary uses ONLY vmcnt(0) (spill-proof) + barrier.   [VERIFIED: rounds 6/8]
// MODE 2: eh = relu(acc+be1)*wsel -> LDS -> GEMM2 vs We2t[e] -> f32 partial[by][e][256][32]
template<int MODE>
__global__ __launch_bounds__(512, 2)
void gemm256(const short* __restrict__ A, const short* __restrict__ Bt,
             const float* __restrict__ bias, const float* __restrict__ wselp,
             const short* __restrict__ W2, short* __restrict__ C,
             float* __restrict__ pout, const float* __restrict__ bias2,
             short* __restrict__ C2, int M, int N, int K) {
    extern __shared__ __align__(16) short lds[];
    const int tid = threadIdx.x;
    const int w = tid >> 6, lane = tid & 63;
    const int wr = w >> 2, wc = w & 3;

    const int gx = gridDim.x;
    const int b = blockIdx.y * gx + blockIdx.x;
    int bx, by;
    {
        // bijective XCD swizzle (nwg % 8 == 0 for all our launches)
        const int per = (gx * gridDim.y) >> 3;
        const int sb = (b & 7) * per + (b >> 3);
        bx = sb % gx; by = sb / gx;
    }
    const int tm = by * 256, tn = bx * 256;

    const int rih = w * 8 + (lane >> 3);
    const int colel = (((lane & 7) ^ (lane >> 3)) << 3);
    const short* pA = A + (size_t)(tm + rih) * K + colel;
    const short* pB = Bt + (size_t)(tn + rih) * K + colel;
    const size_t rK64 = (size_t)64 * K, rK128 = (size_t)128 * K;
    short* const ldsw = lds + w * 512;

#define STG_A(buf, h, t) do { \
        const short* s_ = pA + (size_t)(h) * rK128 + (size_t)(t) * 64; \
        short* d_ = ldsw + (buf) * 32768 + (h) * 8192; \
        gload16(s_, d_); \
        gload16(s_ + rK64, d_ + 4096); } while (0)
#define STG_B(buf, h, t) do { \
        const short* s_ = pB + (size_t)(h) * rK128 + (size_t)(t) * 64; \
        short* d_ = ldsw + (buf) * 32768 + 16384 + (h) * 8192; \
        gload16(s_, d_); \
        gload16(s_ + rK64, d_ + 4096); } while (0)

    const int rA = lane & 15, q = lane >> 4;
    const int csw0 = ((q << 4)) ^ ((lane & 7) << 4);
    const int csw1 = (64 + (q << 4)) ^ ((lane & 7) << 4);
    const char* const ldsB_ = (const char*)lds;
    const int aBase0 = wr * 16384 + rA * 128;
    const int bBase0 = 32768 + (wc >> 1) * 16384 + ((wc & 1) * 64 + rA) * 128;

    f32x4 acc[8][4] = {};
    short8 aL[4][2], aH[4][2], b0[2][2], b1[2][2];
    const int nt = K >> 6;

    // prologue: stage tile0; then initial aL/b0 reads
    STG_A(0, 0, 0); STG_A(0, 1, 0); STG_B(0, 0, 0); STG_B(0, 1, 0);
    WAITV0(); BAR();
    {
        const char* pa = ldsB_ + aBase0;
        const char* pb = ldsB_ + bBase0;
#pragma unroll
        for (int m = 0; m < 4; m++) {
            aL[m][0] = *(const short8*)(pa + m * 2048 + csw0);
            aL[m][1] = *(const short8*)(pa + m * 2048 + csw1);
        }
#pragma unroll
        for (int n = 0; n < 2; n++) {
            b0[n][0] = *(const short8*)(pb + n * 2048 + csw0);
            b0[n][1] = *(const short8*)(pb + n * 2048 + csw1);
        }
    }

    for (int t = 0; t < nt; ++t) {
        const int cur = t & 1, nxt = cur ^ 1;
        const char* pa = ldsB_ + cur * 65536 + aBase0;
        const char* pb = ldsB_ + cur * 65536 + bBase0;
        // ph1: issue b1 reads + next-tile staging; MFMA (lo,lo) on aL,b0
#pragma unroll
        for (int n = 0; n < 2; n++) {
            b1[n][0] = *(const short8*)(pb + (2 + n) * 2048 + csw0);
            b1[n][1] = *(const short8*)(pb + (2 + n) * 2048 + csw1);
        }
        if (t + 1 < nt) {
            STG_A(nxt, 0, t + 1); STG_A(nxt, 1, t + 1);
            STG_B(nxt, 0, t + 1); STG_B(nxt, 1, t + 1);
        }
        __builtin_amdgcn_s_setprio(1);
#pragma unroll
        for (int m = 0; m < 4; m++)
#pragma unroll
            for (int n = 0; n < 2; n++) {
                acc[m][n] = __builtin_amdgcn_mfma_f32_16x16x32_bf16(aL[m][0], b0[n][0], acc[m][n], 0, 0, 0);
                acc[m][n] = __builtin_amdgcn_mfma_f32_16x16x32_bf16(aL[m][1], b0[n][1], acc[m][n], 0, 0, 0);
            }
        __builtin_amdgcn_s_setprio(0);
        // ph2: issue aH reads; MFMA (lo,hi) on aL,b1
#pragma unroll
        for (int m = 0; m < 4; m++) {
            aH[m][0] = *(const short8*)(pa + (4 + m) * 2048 + csw0);
            aH[m][1] = *(const short8*)(pa + (4 + m) * 2048 + csw1);
        }
        __builtin_amdgcn_s_setprio(1);
#pragma unroll
        for (int m = 0; m < 4; m++)
#pragma unroll
            for (int n = 0; n < 2; n++) {
                acc[m][2 + n] = __builtin_amdgcn_mfma_f32_16x16x32_bf16(aL[m][0], b1[n][0], acc[m][2 + n], 0, 0, 0);
                acc[m][2 + n] = __builtin_amdgcn_mfma_f32_16x16x32_bf16(aL[m][1], b1[n][1], acc[m][2 + n], 0, 0, 0);
            }
        __builtin_amdgcn_s_setprio(0);
        // ph3: MFMA (hi,hi) on aH,b1
        __builtin_amdgcn_s_setprio(1);
#pragma unroll
        for (int m = 0; m < 4; m++)
#pragma unroll
            for (int n = 0; n < 2; n++) {
                acc[4 + m][2 + n] = __builtin_amdgcn_mfma_f32_16x16x32_bf16(aH[m][0], b1[n][0], acc[4 + m][2 + n], 0, 0, 0);
                acc[4 + m][2 + n] = __builtin_amdgcn_mfma_f32_16x16x32_bf16(aH[m][1], b1[n][1], acc[4 + m][2 + n], 0, 0, 0);
            }
        __builtin_amdgcn_s_setprio(0);
        // ph4: MFMA (hi,lo) on aH,b0; boundary
        __builtin_amdgcn_s_setprio(1);
#pragma unroll
        for (int m = 0; m < 4; m++)
#pragma unroll
            for (int n = 0; n < 2; n++) {
                acc[4 + m][n] = __builtin_amdgcn_mfma_f32_16x16x32_bf16(aH[m][0], b0[n][0], acc[4 + m][n], 0, 0, 0);
                acc[4 + m][n] = __builtin_amdgcn_mfma_f32_16x16x32_bf16(aH[m][1], b0[n][1], acc[4 + m][n], 0, 0, 0);
            }
        __builtin_amdgcn_s_setprio(0);
        WAITV0(); BAR();
        // issue next tile's aL/b0 reads (buffer nxt, now resident)
        if (t + 1 < nt) {
            const char* qa = ldsB_ + nxt * 65536 + aBase0;
            const char* qb = ldsB_ + nxt * 65536 + bBase0;
#pragma unroll
            for (int m = 0; m < 4; m++) {
                aL[m][0] = *(const short8*)(qa + m * 2048 + csw0);
                aL[m][1] = *(const short8*)(qa + m * 2048 + csw1);
            }
#pragma unroll
            for (int n = 0; n < 2; n++) {
                b0[n][0] = *(const short8*)(qb + n * 2048 + csw0);
                b0[n][1] = *(const short8*)(qb + n * 2048 + csw1);
            }
        }
    }
#undef STG_A
#undef STG_B

    const int q4 = q * 4;
    float biasv[4];
#pragma unroll
    for (int n = 0; n < 4; n++) {
        const int col = tn + wc * 64 + n * 16 + rA;
        biasv[n] = bias[col];
    }

    if (MODE == 2) {
        // eh -> LDS (bf16, wsel-scaled, XOR-swizzled), whole 128KB
        const int e = tn >> 8;
        char* ldsc = (char*)lds;
#pragma unroll
        for (int m = 0; m < 8; m++)
#pragma unroll
            for (int rr = 0; rr < 4; rr++) {
                const int row = wr * 128 + m * 16 + q4 + rr;
                const float ws = wselp[(size_t)(tm + row) * 16 + e];
#pragma unroll
                for (int n = 0; n < 4; n++) {
                    const int col = wc * 64 + n * 16 + rA;
                    const float v = fmaxf(acc[m][n][rr] + biasv[n], 0.f) * ws;
                    *(short*)(ldsc + row * 512 + ((col * 2) ^ ((row & 7) << 4))) = f2b(v);
                }
            }
        asm volatile("s_waitcnt lgkmcnt(0)" ::: "memory");
        BAR();
        f32x4 g2[2][2] = {};
#pragma unroll
        for (int k2 = 0; k2 < 8; ++k2) {
            short8 a2[2], b2[2];
#pragma unroll
            for (int m2 = 0; m2 < 2; m2++) {
                const int row = w * 32 + m2 * 16 + rA;
                a2[m2] = *(const short8*)(ldsc + row * 512 + ((k2 * 64 + q * 16) ^ ((row & 7) << 4)));
            }
#pragma unroll
            for (int n2 = 0; n2 < 2; n2++)
                b2[n2] = *(const short8*)(W2 + (size_t)(e * 32 + n2 * 16 + rA) * 256 + k2 * 32 + q * 8);
#pragma unroll
            for (int m2 = 0; m2 < 2; m2++)
#pragma unroll
                for (int n2 = 0; n2 < 2; n2++)
                    g2[m2][n2] = __builtin_amdgcn_mfma_f32_16x16x32_bf16(a2[m2], b2[n2], g2[m2][n2], 0, 0, 0);
        }
        float* pp = pout + ((size_t)(tm >> 8) * 16 + e) * 8192;
#pragma unroll
        for (int m2 = 0; m2 < 2; m2++)
#pragma unroll
            for (int rr = 0; rr < 4; rr++) {
                const int row = w * 32 + m2 * 16 + q4 + rr;
#pragma unroll
                for (int n2 = 0; n2 < 2; n2++)
                    pp[row * 32 + n2 * 16 + rA] = g2[m2][n2][rr];
            }
        return;
    }

    // MODE 0 epilogue (unused in current launch set, kept for completeness)
#pragma unroll
    for (int m = 0; m < 8; m++)
#pragma unroll
        for (int rr = 0; rr < 4; rr++) {
            const int row = tm + wr * 128 + m * 16 + q4 + rr;
#pragma unroll
            for (int n = 0; n < 4; n++) {
                const int col = tn + wc * 64 + n * 16 + rA;
                float v = fmaxf(acc[m][n][rr] + biasv[n], 0.f);
                C[(size_t)row * N + col] = f2b(v);
            }
        }
}

extern "C" void kernel_launch(void* const* d_in, const int* in_sizes, int n_in,
                              void* d_out, int out_size, void* d_ws, size_t ws_size,
                              hipStream_t stream) {
    const float* obs = (const float*)d_in[0];
    const float* Wb0 = (const float*)d_in[1]; const float* bb0 = (const float*)d_in[2];
    const float* Wb1 = (const float*)d_in[3]; const float* bb1 = (const float*)d_in[4];
    const float* Wb2 = (const float*)d_in[5]; const float* bb2 = (const float*)d_in[6];
    const float* We1 = (const float*)d_in[7]; const float* be1 = (const float*)d_in[8];
    const float* We2 = (const float*)d_in[9]; const float* be2 = (const float*)d_in[10];
    const float* Ws0 = (const float*)d_in[11]; const float* bs0 = (const float*)d_in[12];
    const float* Ws1 = (const float*)d_in[13]; const float* bs1 = (const float*)d_in[14];
    const float* Ws2 = (const float*)d_in[15]; const float* bs2 = (const float*)d_in[16];

    const int B = 65536;
    char* ws = (char*)d_ws;
    size_t off = 0;
    auto alloc = [&](size_t bytes) { void* p = ws + off; off += (bytes + 255) & ~(size_t)255; return p; };
    short* obs_bf = (short*)alloc((size_t)B * 512 * 2);
    short* h1     = (short*)alloc((size_t)B * 1024 * 2);   // dead after Wb1; reused as partial
    short* h2     = (short*)alloc((size_t)B * 1024 * 2);   // dead after Wb2; partial tail
    short* hbuf   = (short*)alloc((size_t)B * 512 * 2);
    short* s0     = (short*)alloc((size_t)B * 256 * 2);
    float* wsel   = (float*)alloc((size_t)B * 16 * 4);
    short* WbS0t  = (short*)alloc((size_t)1280 * 512 * 2); // [Wb0t(1024) ; Ws0t(256)]
    short* Wb1t   = (short*)alloc((size_t)1024 * 1024 * 2);
    short* Wb2t   = (short*)alloc((size_t)1024 * 512 * 2);
    short* We1t   = (short*)alloc((size_t)16 * 512 * 256 * 2);
    short* We2t   = (short*)alloc((size_t)16 * 256 * 32 * 2);
    short* Ws1t   = (short*)alloc((size_t)256 * 128 * 2);
    short* Ws2t   = (short*)alloc((size_t)128 * 16 * 2);
    float* partial = (float*)h1;   // [256][16][256][32] f32 = 134 MB

    static int inited = 0;
    if (!inited) {
        hipFuncSetAttribute(reinterpret_cast<const void*>(gemm256<2>),
                            hipFuncAttributeMaxDynamicSharedMemorySize, 131072);
        inited = 1;
    }

    // --- preprocessing: casts / transposes ---
    cast_bf16_kernel<<<(B * 512 / 8 + 255) / 256, 256, 0, stream>>>(obs, obs_bf, B * 512 / 8);
    transpose_cast_kernel<<<dim3((1024 * 512 / 8 + 255) / 256, 1), 256, 0, stream>>>(Wb0, WbS0t, 512, 1024, 1024 * 512 / 8);
    transpose_cast_kernel<<<dim3((256 * 512 / 8 + 255) / 256, 1), 256, 0, stream>>>(Ws0, WbS0t + (size_t)1024 * 512, 512, 256, 256 * 512 / 8);
    transpose_cast_kernel<<<dim3((1024 * 1024 / 8 + 255) / 256, 1), 256, 0, stream>>>(Wb1, Wb1t, 1024, 1024, 1024 * 1024 / 8);
    transpose_cast_kernel<<<dim3((512 * 1024 / 8 + 255) / 256, 1), 256, 0, stream>>>(Wb2, Wb2t, 1024, 512, 512 * 1024 / 8);
    transpose_cast_kernel<<<dim3((256 * 512 / 8 + 255) / 256, 16), 256, 0, stream>>>(We1, We1t, 512, 256, 256 * 512 / 8);
    transpose_cast_kernel<<<dim3((32 * 256 / 8 + 255) / 256, 16), 256, 0, stream>>>(We2, We2t, 256, 32, 32 * 256 / 8);
    transpose_cast_kernel<<<dim3((128 * 256 / 8 + 255) / 256, 1), 256, 0, stream>>>(Ws1, Ws1t, 256, 128, 128 * 256 / 8);
    transpose_cast_kernel<<<dim3((16 * 128 / 8 + 255) / 256, 1), 256, 0, stream>>>(Ws2, Ws2t, 128, 16, 16 * 128 / 8);

    // --- Wb0 + selector-L0 fused (128², dual output h1 / s0). N=1024 is the
    //     C row-stride (R9 bug was passing 1280); grid x=10 covers 1280 cols. ---
    gemm_bt_bias_relu<1><<<dim3(10, B / 128), 256, 0, stream>>>(
        obs_bf, WbS0t, bb0, h1, bs0, s0, B, 1024, 512);
    // --- selector tail ---
    sel_fused<<<B / 128, 256, 0, stream>>>(s0, Ws1t, bs1, Ws2t, bs2, wsel);

    // --- backbone (128² m97 structure, 3 blocks/CU) ---
    gemm_bt_bias_relu<0><<<dim3(8, B / 128), 256, 0, stream>>>(
        h1, Wb1t, bb1, h2, nullptr, nullptr, B, 1024, 1024);
    gemm_bt_bias_relu<0><<<dim3(4, B / 128), 256, 0, stream>>>(
        h2, Wb2t, bb2, hbuf, nullptr, nullptr, B, 512, 1024);

    // --- experts: single fused dispatch (GEMM1 + in-block GEMM2 -> partials) ---
    gemm256<2><<<dim3(16, B / 256), 512, 131072, stream>>>(
        hbuf, We1t, be1, wsel, We2t, nullptr, partial, nullptr, nullptr, B, 4096, 512);
    // --- final reduce (includes sum_e wsel*be2 init term) ---
    reduce_kernel<<<B * 8 / 256, 256, 0, stream>>>(partial, wsel, be2, (float*)d_out);
}